// Round 2
// baseline (22529.857 us; speedup 1.0000x reference)
//
#include <hip/hip_runtime.h>

// ---------------- problem constants ----------------
#define NN      32768       // nodes
#define EE      524288      // edges
#define GG      256         // graphs
#define NPG     128
#define HID     256
#define KTOP    30
#define TD      769         // HID*3+1
#define HSTR    772         // padded row stride for h (float4 aligned)
#define PLEN    23070       // KTOP*TD
#define C1LEN   23066
#define POOLLEN 11533
#define C2LEN   11529
#define FLAT    368928      // 32*C2LEN
#define L1_KRANGE 1920
#define L1_KS   193         // ceil(FLAT/1920); last chunk = 288 (both %32==0)

// ---------------- graph prep ----------------
__global__ __launch_bounds__(256) void k_deg(const int* __restrict__ dst, int* __restrict__ deg_cnt) {
    int e = blockIdx.x * 256 + threadIdx.x;
    atomicAdd(&deg_cnt[dst[e]], 1);
}

__global__ __launch_bounds__(256) void k_norm(const int* __restrict__ deg_cnt,
                                              float* __restrict__ dinv, float* __restrict__ snorm) {
    int n = blockIdx.x * 256 + threadIdx.x;
    float dg = 1.0f + (float)deg_cnt[n];
    dinv[n] = rsqrtf(dg);
    snorm[n] = 1.0f / dg;
}

// single-block exclusive scan of deg_cnt[NN] -> row_start[NN]
__global__ __launch_bounds__(1024) void k_scan(const int* __restrict__ deg_cnt, int* __restrict__ row_start) {
    __shared__ int sA[1024];
    int t = threadIdx.x;
    int base = t * 32;
    int s = 0;
    for (int i = 0; i < 32; i++) s += deg_cnt[base + i];
    sA[t] = s;
    __syncthreads();
    for (int off = 1; off < 1024; off <<= 1) {
        int v = (t >= off) ? sA[t - off] : 0;
        __syncthreads();
        sA[t] += v;
        __syncthreads();
    }
    int run = sA[t] - s;   // exclusive base for this thread's chunk
    for (int i = 0; i < 32; i++) { row_start[base + i] = run; run += deg_cnt[base + i]; }
}

__global__ __launch_bounds__(256) void k_csrfill(const int* __restrict__ src, const int* __restrict__ dst,
                                                 const int* __restrict__ row_start, int* __restrict__ fill,
                                                 const float* __restrict__ dinv,
                                                 int* __restrict__ csr_src, float* __restrict__ csr_w) {
    int e = blockIdx.x * 256 + threadIdx.x;
    int s = src[e], d = dst[e];
    int pos = row_start[d] + atomicAdd(&fill[d], 1);
    csr_src[pos] = s;
    csr_w[pos] = dinv[s] * dinv[d];
}

__global__ __launch_bounds__(256) void k_embed(const int* __restrict__ z, const float* __restrict__ emb,
                                               float* __restrict__ x) {
    int i = blockIdx.x * 256 + threadIdx.x;   // over NN*64
    int n = i >> 6, l = i & 63;
    ((float4*)x)[(size_t)n * 64 + l] = ((const float4*)emb)[(size_t)z[n] * 64 + l];
}

// ---------------- GCN GEMM: C[M,256] = A[M,256] @ B[256,256] ----------------
// BM=128 BN=128 BK=16, 256 threads, 8x8 per thread
__global__ __launch_bounds__(256) void k_gemm_gcn(const float* __restrict__ A, const float* __restrict__ B,
                                                  float* __restrict__ C) {
    __shared__ float As[16][132];
    __shared__ float Bs[16][132];
    int m0 = blockIdx.x * 128;
    int n0 = blockIdx.y * 128;
    int tid = threadIdx.x;
    int ty = tid >> 4, tx = tid & 15;
    float acc[8][8] = {};
    for (int k0 = 0; k0 < 256; k0 += 16) {
        {
            int m = tid >> 2, kq = (tid & 3) * 4;
            #pragma unroll
            for (int r = 0; r < 2; r++) {
                float4 v = *(const float4*)&A[(size_t)(m0 + m + 64 * r) * 256 + k0 + kq];
                As[kq + 0][m + 64 * r] = v.x;
                As[kq + 1][m + 64 * r] = v.y;
                As[kq + 2][m + 64 * r] = v.z;
                As[kq + 3][m + 64 * r] = v.w;
            }
            int n = (tid & 31) * 4, kk = tid >> 5;
            #pragma unroll
            for (int r = 0; r < 2; r++) {
                float4 v = *(const float4*)&B[(size_t)(k0 + kk + 8 * r) * 256 + n0 + n];
                *(float4*)&Bs[kk + 8 * r][n] = v;
            }
        }
        __syncthreads();
        #pragma unroll
        for (int k = 0; k < 16; k++) {
            float a[8], b[8];
            *(float4*)&a[0] = *(float4*)&As[k][ty * 8];
            *(float4*)&a[4] = *(float4*)&As[k][ty * 8 + 4];
            *(float4*)&b[0] = *(float4*)&Bs[k][tx * 8];
            *(float4*)&b[4] = *(float4*)&Bs[k][tx * 8 + 4];
            #pragma unroll
            for (int i = 0; i < 8; i++)
                #pragma unroll
                for (int j = 0; j < 8; j++) acc[i][j] += a[i] * b[j];
        }
        __syncthreads();
    }
    #pragma unroll
    for (int i = 0; i < 8; i++) {
        int m = m0 + ty * 8 + i;
        float4 v0 = make_float4(acc[i][0], acc[i][1], acc[i][2], acc[i][3]);
        float4 v1 = make_float4(acc[i][4], acc[i][5], acc[i][6], acc[i][7]);
        *(float4*)&C[(size_t)m * 256 + n0 + tx * 8] = v0;
        *(float4*)&C[(size_t)m * 256 + n0 + tx * 8 + 4] = v1;
    }
}

// ---------------- aggregation + tanh, one wave per node ----------------
__global__ __launch_bounds__(256) void k_agg(const float* __restrict__ xw, const int* __restrict__ row_start,
                                             const int* __restrict__ deg_cnt, const int* __restrict__ csr_src,
                                             const float* __restrict__ csr_w, const float* __restrict__ snorm,
                                             const float* __restrict__ bias, float* __restrict__ xn,
                                             float* __restrict__ h, int hoff) {
    int d = blockIdx.x * 4 + (threadIdx.x >> 6);
    int l = threadIdx.x & 63;
    float4 v = ((const float4*)xw)[(size_t)d * 64 + l];
    float sn = snorm[d];
    float4 acc = make_float4(sn * v.x, sn * v.y, sn * v.z, sn * v.w);
    int st = row_start[d], cnt = deg_cnt[d];
    for (int j = 0; j < cnt; j++) {
        int s = csr_src[st + j];
        float w = csr_w[st + j];
        float4 u = ((const float4*)xw)[(size_t)s * 64 + l];
        acc.x += w * u.x; acc.y += w * u.y; acc.z += w * u.z; acc.w += w * u.w;
    }
    float4 b = ((const float4*)bias)[l];
    acc.x = tanhf(acc.x + b.x);
    acc.y = tanhf(acc.y + b.y);
    acc.z = tanhf(acc.z + b.z);
    acc.w = tanhf(acc.w + b.w);
    ((float4*)xn)[(size_t)d * 64 + l] = acc;
    *(float4*)&h[(size_t)d * HSTR + hoff + l * 4] = acc;
}

// last layer: xwl[n] = dot(x[n,:], wl[0:256])
__global__ __launch_bounds__(256) void k_dot_last(const float* __restrict__ x, const float* __restrict__ wl,
                                                  float* __restrict__ xwl) {
    int d = blockIdx.x * 4 + (threadIdx.x >> 6);
    int l = threadIdx.x & 63;
    float4 v = ((const float4*)x)[(size_t)d * 64 + l];
    float4 w = ((const float4*)wl)[l];
    float s = v.x * w.x + v.y * w.y + v.z * w.z + v.w * w.w;
    #pragma unroll
    for (int off = 32; off; off >>= 1) s += __shfl_down(s, off, 64);
    if (l == 0) xwl[d] = s;
}

__global__ __launch_bounds__(256) void k_agg_last(const float* __restrict__ xwl, const int* __restrict__ row_start,
                                                  const int* __restrict__ deg_cnt, const int* __restrict__ csr_src,
                                                  const float* __restrict__ csr_w, const float* __restrict__ snorm,
                                                  const float* __restrict__ blast, float* __restrict__ h) {
    int d = blockIdx.x * 256 + threadIdx.x;
    float acc = snorm[d] * xwl[d];
    int st = row_start[d], cnt = deg_cnt[d];
    for (int j = 0; j < cnt; j++) acc += csr_w[st + j] * xwl[csr_src[st + j]];
    h[(size_t)d * HSTR + 768] = tanhf(acc + blast[0]);
}

// ---------- per-graph stable top-K sort (bitonic over 128) + gather into P ----------
__global__ __launch_bounds__(128) void k_sort_gather(const float* __restrict__ h, float* __restrict__ P) {
    __shared__ float kk[128];
    __shared__ int ii[128];
    int g = blockIdx.x, t = threadIdx.x;
    kk[t] = h[(size_t)(g * 128 + t) * HSTR + 768];
    ii[t] = t;
    __syncthreads();
    for (int size = 2; size <= 128; size <<= 1) {
        for (int stride = size >> 1; stride > 0; stride >>= 1) {
            int p = t ^ stride;
            if (p > t) {
                float ka = kk[t], kbv = kk[p];
                int ia = ii[t], ib = ii[p];
                // aFirst: a precedes b in final order (desc key, asc idx on ties == stable argsort(-key))
                bool aFirst = (ka > kbv) || (ka == kbv && ia < ib);
                bool asc = (t & size) == 0;
                if (asc != aFirst) { kk[t] = kbv; kk[p] = ka; ii[t] = ib; ii[p] = ia; }
            }
            __syncthreads();
        }
    }
    // gather top-K rows of h into P
    float* Pg = P + (size_t)g * PLEN;
    for (int r = 0; r < KTOP; r++) {
        const float* srcp = h + (size_t)(g * 128 + ii[r]) * HSTR;
        for (int c = t; c < TD; c += 128) Pg[(size_t)r * TD + c] = srcp[c];
    }
}

// ---------------- fused conv1 + relu + maxpool2 + conv2 + relu ----------------
// block: one graph g x 256 output positions j. All 32 c2 channels.
#define JT 256
__global__ __launch_bounds__(256) void k_conv(const float* __restrict__ P,
                                              const float* __restrict__ w1, const float* __restrict__ b1,
                                              const float* __restrict__ w2, const float* __restrict__ b2,
                                              float* __restrict__ f) {
    __shared__ float sl[526];
    __shared__ float pool[16][JT + 4];
    __shared__ float w2t[80][32];
    __shared__ float w1s[16][5];
    __shared__ float b1s[16];
    __shared__ float b2s[32];
    int g = blockIdx.x;
    int j0 = blockIdx.y * JT;
    int tid = threadIdx.x;
    const float* Pg = P + (size_t)g * PLEN;
    for (int i = tid; i < 526; i += 256) sl[i] = Pg[min(2 * j0 + i, PLEN - 1)];
    for (int i = tid; i < 80; i += 256) w1s[i / 5][i % 5] = w1[i];
    if (tid < 16) b1s[tid] = b1[tid];
    if (tid < 32) b2s[tid] = b2[tid];
    for (int i = tid; i < 2560; i += 256) {
        int c2 = i / 80, rem = i % 80;     // rem = c1*5+k
        w2t[rem][c2] = w2[i];
    }
    __syncthreads();
    // build pool values for local positions t in [0, JT+4)
    for (int i = tid; i < 16 * (JT + 4); i += 256) {
        int c1 = i / (JT + 4), t = i % (JT + 4);
        int u = 2 * t;
        float a = b1s[c1], b = b1s[c1];
        #pragma unroll
        for (int q = 0; q < 5; q++) {
            a += w1s[c1][q] * sl[u + q];
            b += w1s[c1][q] * sl[u + 1 + q];
        }
        pool[c1][t] = fmaxf(fmaxf(a, b), 0.0f);
    }
    __syncthreads();
    // conv2: wave wv handles c2 block [wv*8, wv*8+8), lane jl handles 4 j positions
    int wv = tid >> 6;
    int jl = tid & 63;
    int c2o = wv * 8;
    float acc[8][4];
    #pragma unroll
    for (int cc = 0; cc < 8; cc++) {
        float bb = b2s[c2o + cc];
        #pragma unroll
        for (int jj = 0; jj < 4; jj++) acc[cc][jj] = bb;
    }
    #pragma unroll
    for (int c1 = 0; c1 < 16; c1++) {
        #pragma unroll
        for (int k = 0; k < 5; k++) {
            float4 w0 = *(float4*)&w2t[c1 * 5 + k][c2o];
            float4 w1v = *(float4*)&w2t[c1 * 5 + k][c2o + 4];
            float p0 = pool[c1][jl + k];
            float p1 = pool[c1][jl + 64 + k];
            float p2 = pool[c1][jl + 128 + k];
            float p3 = pool[c1][jl + 192 + k];
            acc[0][0] += w0.x * p0; acc[0][1] += w0.x * p1; acc[0][2] += w0.x * p2; acc[0][3] += w0.x * p3;
            acc[1][0] += w0.y * p0; acc[1][1] += w0.y * p1; acc[1][2] += w0.y * p2; acc[1][3] += w0.y * p3;
            acc[2][0] += w0.z * p0; acc[2][1] += w0.z * p1; acc[2][2] += w0.z * p2; acc[2][3] += w0.z * p3;
            acc[3][0] += w0.w * p0; acc[3][1] += w0.w * p1; acc[3][2] += w0.w * p2; acc[3][3] += w0.w * p3;
            acc[4][0] += w1v.x * p0; acc[4][1] += w1v.x * p1; acc[4][2] += w1v.x * p2; acc[4][3] += w1v.x * p3;
            acc[5][0] += w1v.y * p0; acc[5][1] += w1v.y * p1; acc[5][2] += w1v.y * p2; acc[5][3] += w1v.y * p3;
            acc[6][0] += w1v.z * p0; acc[6][1] += w1v.z * p1; acc[6][2] += w1v.z * p2; acc[6][3] += w1v.z * p3;
            acc[7][0] += w1v.w * p0; acc[7][1] += w1v.w * p1; acc[7][2] += w1v.w * p2; acc[7][3] += w1v.w * p3;
        }
    }
    size_t fg = (size_t)g * FLAT;
    #pragma unroll
    for (int cc = 0; cc < 8; cc++) {
        #pragma unroll
        for (int jj = 0; jj < 4; jj++) {
            int j = j0 + jl + 64 * jj;
            if (j < C2LEN) f[fg + (size_t)(c2o + cc) * C2LEN + j] = fmaxf(acc[cc][jj], 0.0f);
        }
    }
}

// ---------------- lin1 split-K GEMM: C[256,128] = f[256,FLAT] @ W[128,FLAT]^T ----------------
// BM=64 BN=128 BK=32, 256 threads, 8x4 per thread. grid (4, L1_KS) -> partial[ks][256][128]
__global__ __launch_bounds__(256) void k_lin1(const float* __restrict__ f, const float* __restrict__ W,
                                              float* __restrict__ partial) {
    __shared__ float As[32][68];
    __shared__ float Bs[32][132];
    int m0 = blockIdx.x * 64;
    int ks = blockIdx.y;
    int kbase = ks * L1_KRANGE;
    int kend = min(kbase + L1_KRANGE, FLAT);
    int tid = threadIdx.x;
    int ty = tid >> 5, tx = tid & 31;
    float acc[8][4] = {};
    for (int k0 = kbase; k0 < kend; k0 += 32) {
        {
            int m = tid >> 2, kq = (tid & 3) * 8;
            #pragma unroll
            for (int r = 0; r < 2; r++) {
                int k = kq + r * 4;
                float4 v = *(const float4*)&f[(size_t)(m0 + m) * FLAT + k0 + k];
                As[k + 0][m] = v.x; As[k + 1][m] = v.y; As[k + 2][m] = v.z; As[k + 3][m] = v.w;
            }
            int n = tid >> 3, kq2 = (tid & 7) * 4;
            #pragma unroll
            for (int r = 0; r < 4; r++) {
                int nn = n + 32 * r;
                float4 v = *(const float4*)&W[(size_t)nn * FLAT + k0 + kq2];
                Bs[kq2 + 0][nn] = v.x; Bs[kq2 + 1][nn] = v.y; Bs[kq2 + 2][nn] = v.z; Bs[kq2 + 3][nn] = v.w;
            }
        }
        __syncthreads();
        #pragma unroll
        for (int k = 0; k < 32; k++) {
            float a[8], bv[4];
            *(float4*)&a[0] = *(float4*)&As[k][ty * 8];
            *(float4*)&a[4] = *(float4*)&As[k][ty * 8 + 4];
            *(float4*)&bv[0] = *(float4*)&Bs[k][tx * 4];
            #pragma unroll
            for (int i = 0; i < 8; i++)
                #pragma unroll
                for (int j = 0; j < 4; j++) acc[i][j] += a[i] * bv[j];
        }
        __syncthreads();
    }
    #pragma unroll
    for (int i = 0; i < 8; i++) {
        int m = m0 + ty * 8 + i;
        float4 v = make_float4(acc[i][0], acc[i][1], acc[i][2], acc[i][3]);
        *(float4*)&partial[((size_t)ks * 256 + m) * 128 + tx * 4] = v;
    }
}

// ---------------- reduce partials + relu + lin2 ----------------
__global__ __launch_bounds__(128) void k_reduce(const float* __restrict__ partial, const float* __restrict__ lb1,
                                                const float* __restrict__ lw2, const float* __restrict__ lb2,
                                                float* __restrict__ out) {
    int g = blockIdx.x, o = threadIdx.x;
    float s = 0.0f;
    for (int ks = 0; ks < L1_KS; ks++) s += partial[((size_t)ks * 256 + g) * 128 + o];
    float v = fmaxf(s + lb1[o], 0.0f) * lw2[o];
    #pragma unroll
    for (int off = 32; off; off >>= 1) v += __shfl_down(v, off, 64);
    __shared__ float red[2];
    if ((threadIdx.x & 63) == 0) red[threadIdx.x >> 6] = v;
    __syncthreads();
    if (threadIdx.x == 0) out[g] = red[0] + red[1] + lb2[0];
}

// ---------------- host launch ----------------
extern "C" void kernel_launch(void* const* d_in, const int* in_sizes, int n_in,
                              void* d_out, int out_size, void* d_ws, size_t ws_size,
                              hipStream_t stream) {
    const int*   z     = (const int*)d_in[0];
    const int*   ei    = (const int*)d_in[1];
    const int*   srcv  = ei;
    const int*   dstv  = ei + EE;
    const float* emb   = (const float*)d_in[3];
    const float* gcnw  = (const float*)d_in[4];
    const float* gcnb  = (const float*)d_in[5];
    const float* wlast = (const float*)d_in[6];
    const float* blast = (const float*)d_in[7];
    const float* w1    = (const float*)d_in[8];
    const float* b1    = (const float*)d_in[9];
    const float* w2    = (const float*)d_in[10];
    const float* b2    = (const float*)d_in[11];
    const float* l1w   = (const float*)d_in[12];
    const float* l1b   = (const float*)d_in[13];
    const float* l2w   = (const float*)d_in[14];
    const float* l2b   = (const float*)d_in[15];
    float* out = (float*)d_out;

    // ---- workspace layout with aliasing (~414 MB total) ----
    // fbuf occupies [0, FB). All stage-1 buffers live INSIDE [0, FB): they are
    // dead before k_conv writes fbuf (last stage-1 reader is k_sort_gather).
    // P and partial live after FB (P is read by k_conv while fbuf is written).
    char* base = (char*)d_ws;
    const size_t FB = ((size_t)GG * FLAT * 4 + 511) & ~(size_t)511;   // 377.8 MB
    float* fbuf = (float*)base;
    char* p = base;
    auto alloc = [&](size_t bytes) { void* r = (void*)p; p += (bytes + 511) & ~(size_t)511; return r; };
    int*   deg_cnt = (int*)  alloc((size_t)NN * 4);
    int*   fill    = (int*)  alloc((size_t)NN * 4);
    int*   rowst   = (int*)  alloc((size_t)NN * 4);
    int*   csr_src = (int*)  alloc((size_t)EE * 4);
    float* csr_w   = (float*)alloc((size_t)EE * 4);
    float* dinv    = (float*)alloc((size_t)NN * 4);
    float* snorm   = (float*)alloc((size_t)NN * 4);
    float* xA      = (float*)alloc((size_t)NN * 256 * 4);
    float* xB      = (float*)alloc((size_t)NN * 256 * 4);
    float* xw      = (float*)alloc((size_t)NN * 256 * 4);
    float* h       = (float*)alloc((size_t)NN * HSTR * 4);
    float* xwl     = (float*)alloc((size_t)NN * 4);
    // stage-1 total ~207 MB < FB (378 MB): fits inside the fbuf overlay region.
    float* P       = (float*)(base + FB);
    float* partial = (float*)(base + FB + (((size_t)GG * PLEN * 4 + 511) & ~(size_t)511));
    (void)ws_size; (void)in_sizes; (void)n_in; (void)out_size;

    hipMemsetAsync(deg_cnt, 0, (size_t)NN * 4, stream);
    hipMemsetAsync(fill,    0, (size_t)NN * 4, stream);

    k_deg    <<<EE / 256, 256, 0, stream>>>(dstv, deg_cnt);
    k_norm   <<<NN / 256, 256, 0, stream>>>(deg_cnt, dinv, snorm);
    k_scan   <<<1, 1024, 0, stream>>>(deg_cnt, rowst);
    k_csrfill<<<EE / 256, 256, 0, stream>>>(srcv, dstv, rowst, fill, dinv, csr_src, csr_w);
    k_embed  <<<NN * 64 / 256, 256, 0, stream>>>(z, emb, xA);

    float* xc = xA;
    float* xn = xB;
    for (int layer = 0; layer < 3; layer++) {
        k_gemm_gcn<<<dim3(NN / 128, 2), 256, 0, stream>>>(xc, gcnw + (size_t)layer * 65536, xw);
        k_agg<<<NN / 4, 256, 0, stream>>>(xw, rowst, deg_cnt, csr_src, csr_w, snorm,
                                          gcnb + layer * 256, xn, h, layer * 256);
        float* t = xc; xc = xn; xn = t;
    }
    k_dot_last<<<NN / 4, 256, 0, stream>>>(xc, wlast, xwl);
    k_agg_last<<<NN / 256, 256, 0, stream>>>(xwl, rowst, deg_cnt, csr_src, csr_w, snorm, blast, h);

    k_sort_gather<<<GG, 128, 0, stream>>>(h, P);

    k_conv<<<dim3(GG, (C2LEN + JT - 1) / JT), 256, 0, stream>>>(P, w1, b1, w2, b2, fbuf);

    k_lin1  <<<dim3(4, L1_KS), 256, 0, stream>>>(fbuf, l1w, partial);
    k_reduce<<<GG, 128, 0, stream>>>(partial, l1b, l2w, l2b, out);
}

// Round 3
// 1476.833 us; speedup vs baseline: 15.2555x; 15.2555x over previous
//
#include <hip/hip_runtime.h>

// ---------------- problem constants ----------------
#define NN      32768       // nodes
#define EE      524288      // edges
#define GG      256         // graphs
#define NPG     128
#define HID     256
#define KTOP    30
#define TD      769         // HID*3+1
#define HSTR    772         // padded row stride for h (float4 aligned)
#define PLEN    23070       // KTOP*TD
#define C1LEN   23066
#define POOLLEN 11533
#define C2LEN   11529
#define FLAT    368928      // 32*C2LEN
#define L1_KRANGE 1920
#define L1_KS   193         // ceil(FLAT/1920); last chunk = 288 (both %32==0)

// ---------------- graph prep ----------------
__global__ __launch_bounds__(256) void k_deg(const int* __restrict__ dst, int* __restrict__ deg_cnt) {
    int e = blockIdx.x * 256 + threadIdx.x;
    atomicAdd(&deg_cnt[dst[e]], 1);
}

__global__ __launch_bounds__(256) void k_norm(const int* __restrict__ deg_cnt,
                                              float* __restrict__ dinv, float* __restrict__ snorm) {
    int n = blockIdx.x * 256 + threadIdx.x;
    float dg = 1.0f + (float)deg_cnt[n];
    dinv[n] = rsqrtf(dg);
    snorm[n] = 1.0f / dg;
}

// single-block exclusive scan of deg_cnt[NN] -> row_start[NN]
__global__ __launch_bounds__(1024) void k_scan(const int* __restrict__ deg_cnt, int* __restrict__ row_start) {
    __shared__ int sA[1024];
    int t = threadIdx.x;
    int base = t * 32;
    int s = 0;
    for (int i = 0; i < 32; i++) s += deg_cnt[base + i];
    sA[t] = s;
    __syncthreads();
    for (int off = 1; off < 1024; off <<= 1) {
        int v = (t >= off) ? sA[t - off] : 0;
        __syncthreads();
        sA[t] += v;
        __syncthreads();
    }
    int run = sA[t] - s;   // exclusive base for this thread's chunk
    for (int i = 0; i < 32; i++) { row_start[base + i] = run; run += deg_cnt[base + i]; }
}

__global__ __launch_bounds__(256) void k_csrfill(const int* __restrict__ src, const int* __restrict__ dst,
                                                 const int* __restrict__ row_start, int* __restrict__ fill,
                                                 const float* __restrict__ dinv,
                                                 int* __restrict__ csr_src, float* __restrict__ csr_w) {
    int e = blockIdx.x * 256 + threadIdx.x;
    int s = src[e], d = dst[e];
    int pos = row_start[d] + atomicAdd(&fill[d], 1);
    csr_src[pos] = s;
    csr_w[pos] = dinv[s] * dinv[d];
}

__global__ __launch_bounds__(256) void k_embed(const int* __restrict__ z, const float* __restrict__ emb,
                                               float* __restrict__ x) {
    int i = blockIdx.x * 256 + threadIdx.x;   // over NN*64
    int n = i >> 6, l = i & 63;
    ((float4*)x)[(size_t)n * 64 + l] = ((const float4*)emb)[(size_t)z[n] * 64 + l];
}

// ---------------- GCN GEMM: C[M,256] = A[M,256] @ B[256,256] ----------------
// BM=128 BN=128 BK=16, 256 threads, 8x8 per thread
__global__ __launch_bounds__(256) void k_gemm_gcn(const float* __restrict__ A, const float* __restrict__ B,
                                                  float* __restrict__ C) {
    __shared__ float As[16][132];
    __shared__ float Bs[16][132];
    int m0 = blockIdx.x * 128;
    int n0 = blockIdx.y * 128;
    int tid = threadIdx.x;
    int ty = tid >> 4, tx = tid & 15;
    float acc[8][8] = {};
    for (int k0 = 0; k0 < 256; k0 += 16) {
        {
            int m = tid >> 2, kq = (tid & 3) * 4;
            #pragma unroll
            for (int r = 0; r < 2; r++) {
                float4 v = *(const float4*)&A[(size_t)(m0 + m + 64 * r) * 256 + k0 + kq];
                As[kq + 0][m + 64 * r] = v.x;
                As[kq + 1][m + 64 * r] = v.y;
                As[kq + 2][m + 64 * r] = v.z;
                As[kq + 3][m + 64 * r] = v.w;
            }
            int n = (tid & 31) * 4, kk = tid >> 5;
            #pragma unroll
            for (int r = 0; r < 2; r++) {
                float4 v = *(const float4*)&B[(size_t)(k0 + kk + 8 * r) * 256 + n0 + n];
                *(float4*)&Bs[kk + 8 * r][n] = v;
            }
        }
        __syncthreads();
        #pragma unroll
        for (int k = 0; k < 16; k++) {
            float a[8], b[8];
            *(float4*)&a[0] = *(float4*)&As[k][ty * 8];
            *(float4*)&a[4] = *(float4*)&As[k][ty * 8 + 4];
            *(float4*)&b[0] = *(float4*)&Bs[k][tx * 8];
            *(float4*)&b[4] = *(float4*)&Bs[k][tx * 8 + 4];
            #pragma unroll
            for (int i = 0; i < 8; i++)
                #pragma unroll
                for (int j = 0; j < 8; j++) acc[i][j] += a[i] * b[j];
        }
        __syncthreads();
    }
    #pragma unroll
    for (int i = 0; i < 8; i++) {
        int m = m0 + ty * 8 + i;
        float4 v0 = make_float4(acc[i][0], acc[i][1], acc[i][2], acc[i][3]);
        float4 v1 = make_float4(acc[i][4], acc[i][5], acc[i][6], acc[i][7]);
        *(float4*)&C[(size_t)m * 256 + n0 + tx * 8] = v0;
        *(float4*)&C[(size_t)m * 256 + n0 + tx * 8 + 4] = v1;
    }
}

// ---------------- aggregation + tanh, one wave per node ----------------
__global__ __launch_bounds__(256) void k_agg(const float* __restrict__ xw, const int* __restrict__ row_start,
                                             const int* __restrict__ deg_cnt, const int* __restrict__ csr_src,
                                             const float* __restrict__ csr_w, const float* __restrict__ snorm,
                                             const float* __restrict__ bias, float* __restrict__ xn,
                                             float* __restrict__ h, int hoff) {
    int d = blockIdx.x * 4 + (threadIdx.x >> 6);
    int l = threadIdx.x & 63;
    float4 v = ((const float4*)xw)[(size_t)d * 64 + l];
    float sn = snorm[d];
    float4 acc = make_float4(sn * v.x, sn * v.y, sn * v.z, sn * v.w);
    int st = row_start[d], cnt = deg_cnt[d];
    for (int j = 0; j < cnt; j++) {
        int s = csr_src[st + j];
        float w = csr_w[st + j];
        float4 u = ((const float4*)xw)[(size_t)s * 64 + l];
        acc.x += w * u.x; acc.y += w * u.y; acc.z += w * u.z; acc.w += w * u.w;
    }
    float4 b = ((const float4*)bias)[l];
    acc.x = tanhf(acc.x + b.x);
    acc.y = tanhf(acc.y + b.y);
    acc.z = tanhf(acc.z + b.z);
    acc.w = tanhf(acc.w + b.w);
    ((float4*)xn)[(size_t)d * 64 + l] = acc;
    *(float4*)&h[(size_t)d * HSTR + hoff + l * 4] = acc;
}

// last layer: xwl[n] = dot(x[n,:], wl[0:256])
__global__ __launch_bounds__(256) void k_dot_last(const float* __restrict__ x, const float* __restrict__ wl,
                                                  float* __restrict__ xwl) {
    int d = blockIdx.x * 4 + (threadIdx.x >> 6);
    int l = threadIdx.x & 63;
    float4 v = ((const float4*)x)[(size_t)d * 64 + l];
    float4 w = ((const float4*)wl)[l];
    float s = v.x * w.x + v.y * w.y + v.z * w.z + v.w * w.w;
    #pragma unroll
    for (int off = 32; off; off >>= 1) s += __shfl_down(s, off, 64);
    if (l == 0) xwl[d] = s;
}

__global__ __launch_bounds__(256) void k_agg_last(const float* __restrict__ xwl, const int* __restrict__ row_start,
                                                  const int* __restrict__ deg_cnt, const int* __restrict__ csr_src,
                                                  const float* __restrict__ csr_w, const float* __restrict__ snorm,
                                                  const float* __restrict__ blast, float* __restrict__ h) {
    int d = blockIdx.x * 256 + threadIdx.x;
    float acc = snorm[d] * xwl[d];
    int st = row_start[d], cnt = deg_cnt[d];
    for (int j = 0; j < cnt; j++) acc += csr_w[st + j] * xwl[csr_src[st + j]];
    h[(size_t)d * HSTR + 768] = tanhf(acc + blast[0]);
}

// ---------- per-graph stable top-K sort (bitonic over 128) + gather into P ----------
__global__ __launch_bounds__(128) void k_sort_gather(const float* __restrict__ h, float* __restrict__ P) {
    __shared__ float kk[128];
    __shared__ int ii[128];
    int g = blockIdx.x, t = threadIdx.x;
    kk[t] = h[(size_t)(g * 128 + t) * HSTR + 768];
    ii[t] = t;
    __syncthreads();
    for (int size = 2; size <= 128; size <<= 1) {
        for (int stride = size >> 1; stride > 0; stride >>= 1) {
            int p = t ^ stride;
            if (p > t) {
                float ka = kk[t], kbv = kk[p];
                int ia = ii[t], ib = ii[p];
                // aFirst: a precedes b in final order (desc key, asc idx on ties == stable argsort(-key))
                bool aFirst = (ka > kbv) || (ka == kbv && ia < ib);
                bool asc = (t & size) == 0;
                if (asc != aFirst) { kk[t] = kbv; kk[p] = ka; ii[t] = ib; ii[p] = ia; }
            }
            __syncthreads();
        }
    }
    // gather top-K rows of h into P
    float* Pg = P + (size_t)g * PLEN;
    for (int r = 0; r < KTOP; r++) {
        const float* srcp = h + (size_t)(g * 128 + ii[r]) * HSTR;
        for (int c = t; c < TD; c += 128) Pg[(size_t)r * TD + c] = srcp[c];
    }
}

// ---------------- fused conv1 + relu + maxpool2 + conv2 + relu ----------------
// Register-lean rewrite: 8 c2 x 2 j per thread (16 accs), c1 loop NOT fully
// unrolled (round-2 postmortem: full 80-iter unroll spilled -> 30 GB scratch
// traffic, 21 ms). JT=128, grid (GG, 91).
#define JT 128
__global__ __launch_bounds__(256) void k_conv(const float* __restrict__ P,
                                              const float* __restrict__ w1, const float* __restrict__ b1,
                                              const float* __restrict__ w2, const float* __restrict__ b2,
                                              float* __restrict__ f) {
    __shared__ float sl[272];            // conv1 inputs for this tile: [2*j0, 2*j0+267]
    __shared__ float pool[16][136];      // pooled conv1 outputs, local t in [0,132)
    __shared__ float w2t[80][32];        // w2 transposed: [c1*5+k][c2]
    __shared__ float w1s[16][5];
    __shared__ float b1s[16];
    __shared__ float b2s[32];
    int g = blockIdx.x;
    int j0 = blockIdx.y * JT;
    int tid = threadIdx.x;
    const float* Pg = P + (size_t)g * PLEN;
    for (int i = tid; i < 268; i += 256) sl[i] = Pg[min(2 * j0 + i, PLEN - 1)];
    for (int i = tid; i < 80; i += 256) w1s[i / 5][i % 5] = w1[i];
    if (tid < 16) b1s[tid] = b1[tid];
    if (tid < 32) b2s[tid] = b2[tid];
    for (int i = tid; i < 2560; i += 256) {
        int c2 = i / 80, rem = i % 80;     // rem = c1*5+k
        w2t[rem][c2] = w2[i];
    }
    __syncthreads();
    // pool build: local positions t in [0, 132)
    for (int i = tid; i < 16 * 132; i += 256) {
        int c1 = i / 132, t = i % 132;
        int u = 2 * t;
        float a = b1s[c1], b = a;
        #pragma unroll
        for (int q = 0; q < 5; q++) {
            a += w1s[c1][q] * sl[u + q];
            b += w1s[c1][q] * sl[u + 1 + q];
        }
        pool[c1][t] = fmaxf(fmaxf(a, b), 0.0f);
    }
    __syncthreads();
    // conv2: wave wv -> c2 block [wv*8, wv*8+8), lane jl -> j in {j0+jl, j0+jl+64}
    int wv = tid >> 6;
    int jl = tid & 63;
    int c2o = wv * 8;
    float acc[8][2];
    #pragma unroll
    for (int cc = 0; cc < 8; cc++) {
        float bb = b2s[c2o + cc];
        acc[cc][0] = bb; acc[cc][1] = bb;
    }
    #pragma unroll 4
    for (int c1 = 0; c1 < 16; c1++) {
        #pragma unroll
        for (int k = 0; k < 5; k++) {
            float4 w0 = *(float4*)&w2t[c1 * 5 + k][c2o];
            float4 w1v = *(float4*)&w2t[c1 * 5 + k][c2o + 4];
            float p0 = pool[c1][jl + k];
            float p1 = pool[c1][jl + 64 + k];
            acc[0][0] += w0.x * p0; acc[0][1] += w0.x * p1;
            acc[1][0] += w0.y * p0; acc[1][1] += w0.y * p1;
            acc[2][0] += w0.z * p0; acc[2][1] += w0.z * p1;
            acc[3][0] += w0.w * p0; acc[3][1] += w0.w * p1;
            acc[4][0] += w1v.x * p0; acc[4][1] += w1v.x * p1;
            acc[5][0] += w1v.y * p0; acc[5][1] += w1v.y * p1;
            acc[6][0] += w1v.z * p0; acc[6][1] += w1v.z * p1;
            acc[7][0] += w1v.w * p0; acc[7][1] += w1v.w * p1;
        }
    }
    size_t fg = (size_t)g * FLAT;
    #pragma unroll
    for (int cc = 0; cc < 8; cc++) {
        #pragma unroll
        for (int jj = 0; jj < 2; jj++) {
            int j = j0 + jl + 64 * jj;
            if (j < C2LEN) f[fg + (size_t)(c2o + cc) * C2LEN + j] = fmaxf(acc[cc][jj], 0.0f);
        }
    }
}

// ---------------- lin1 split-K GEMM: C[256,128] = f[256,FLAT] @ W[128,FLAT]^T ----------------
// BM=64 BN=128 BK=32, 256 threads, 8x4 per thread. grid (4, L1_KS) -> partial[ks][256][128]
__global__ __launch_bounds__(256) void k_lin1(const float* __restrict__ f, const float* __restrict__ W,
                                              float* __restrict__ partial) {
    __shared__ float As[32][68];
    __shared__ float Bs[32][132];
    int m0 = blockIdx.x * 64;
    int ks = blockIdx.y;
    int kbase = ks * L1_KRANGE;
    int kend = min(kbase + L1_KRANGE, FLAT);
    int tid = threadIdx.x;
    int ty = tid >> 5, tx = tid & 31;
    float acc[8][4] = {};
    for (int k0 = kbase; k0 < kend; k0 += 32) {
        {
            int m = tid >> 2, kq = (tid & 3) * 8;
            #pragma unroll
            for (int r = 0; r < 2; r++) {
                int k = kq + r * 4;
                float4 v = *(const float4*)&f[(size_t)(m0 + m) * FLAT + k0 + k];
                As[k + 0][m] = v.x; As[k + 1][m] = v.y; As[k + 2][m] = v.z; As[k + 3][m] = v.w;
            }
            int n = tid >> 3, kq2 = (tid & 7) * 4;
            #pragma unroll
            for (int r = 0; r < 4; r++) {
                int nn = n + 32 * r;
                float4 v = *(const float4*)&W[(size_t)nn * FLAT + k0 + kq2];
                Bs[kq2 + 0][nn] = v.x; Bs[kq2 + 1][nn] = v.y; Bs[kq2 + 2][nn] = v.z; Bs[kq2 + 3][nn] = v.w;
            }
        }
        __syncthreads();
        #pragma unroll
        for (int k = 0; k < 32; k++) {
            float a[8], bv[4];
            *(float4*)&a[0] = *(float4*)&As[k][ty * 8];
            *(float4*)&a[4] = *(float4*)&As[k][ty * 8 + 4];
            *(float4*)&bv[0] = *(float4*)&Bs[k][tx * 4];
            #pragma unroll
            for (int i = 0; i < 8; i++)
                #pragma unroll
                for (int j = 0; j < 4; j++) acc[i][j] += a[i] * bv[j];
        }
        __syncthreads();
    }
    #pragma unroll
    for (int i = 0; i < 8; i++) {
        int m = m0 + ty * 8 + i;
        float4 v = make_float4(acc[i][0], acc[i][1], acc[i][2], acc[i][3]);
        *(float4*)&partial[((size_t)ks * 256 + m) * 128 + tx * 4] = v;
    }
}

// ---------------- reduce partials + relu + lin2 ----------------
__global__ __launch_bounds__(128) void k_reduce(const float* __restrict__ partial, const float* __restrict__ lb1,
                                                const float* __restrict__ lw2, const float* __restrict__ lb2,
                                                float* __restrict__ out) {
    int g = blockIdx.x, o = threadIdx.x;
    float s = 0.0f;
    for (int ks = 0; ks < L1_KS; ks++) s += partial[((size_t)ks * 256 + g) * 128 + o];
    float v = fmaxf(s + lb1[o], 0.0f) * lw2[o];
    #pragma unroll
    for (int off = 32; off; off >>= 1) v += __shfl_down(v, off, 64);
    __shared__ float red[2];
    if ((threadIdx.x & 63) == 0) red[threadIdx.x >> 6] = v;
    __syncthreads();
    if (threadIdx.x == 0) out[g] = red[0] + red[1] + lb2[0];
}

// ---------------- host launch ----------------
extern "C" void kernel_launch(void* const* d_in, const int* in_sizes, int n_in,
                              void* d_out, int out_size, void* d_ws, size_t ws_size,
                              hipStream_t stream) {
    const int*   z     = (const int*)d_in[0];
    const int*   ei    = (const int*)d_in[1];
    const int*   srcv  = ei;
    const int*   dstv  = ei + EE;
    const float* emb   = (const float*)d_in[3];
    const float* gcnw  = (const float*)d_in[4];
    const float* gcnb  = (const float*)d_in[5];
    const float* wlast = (const float*)d_in[6];
    const float* blast = (const float*)d_in[7];
    const float* w1    = (const float*)d_in[8];
    const float* b1    = (const float*)d_in[9];
    const float* w2    = (const float*)d_in[10];
    const float* b2    = (const float*)d_in[11];
    const float* l1w   = (const float*)d_in[12];
    const float* l1b   = (const float*)d_in[13];
    const float* l2w   = (const float*)d_in[14];
    const float* l2b   = (const float*)d_in[15];
    float* out = (float*)d_out;

    // ---- workspace layout with aliasing (~414 MB total) ----
    // fbuf occupies [0, FB). All stage-1 buffers live INSIDE [0, FB): they are
    // dead before k_conv writes fbuf (last stage-1 reader is k_sort_gather).
    // P and partial live after FB (P is read by k_conv while fbuf is written).
    char* base = (char*)d_ws;
    const size_t FB = ((size_t)GG * FLAT * 4 + 511) & ~(size_t)511;   // 377.8 MB
    float* fbuf = (float*)base;
    char* p = base;
    auto alloc = [&](size_t bytes) { void* r = (void*)p; p += (bytes + 511) & ~(size_t)511; return r; };
    int*   deg_cnt = (int*)  alloc((size_t)NN * 4);
    int*   fill    = (int*)  alloc((size_t)NN * 4);
    int*   rowst   = (int*)  alloc((size_t)NN * 4);
    int*   csr_src = (int*)  alloc((size_t)EE * 4);
    float* csr_w   = (float*)alloc((size_t)EE * 4);
    float* dinv    = (float*)alloc((size_t)NN * 4);
    float* snorm   = (float*)alloc((size_t)NN * 4);
    float* xA      = (float*)alloc((size_t)NN * 256 * 4);
    float* xB      = (float*)alloc((size_t)NN * 256 * 4);
    float* xw      = (float*)alloc((size_t)NN * 256 * 4);
    float* h       = (float*)alloc((size_t)NN * HSTR * 4);
    float* xwl     = (float*)alloc((size_t)NN * 4);
    // stage-1 total ~207 MB < FB (378 MB): fits inside the fbuf overlay region.
    float* P       = (float*)(base + FB);
    float* partial = (float*)(base + FB + (((size_t)GG * PLEN * 4 + 511) & ~(size_t)511));
    (void)ws_size; (void)in_sizes; (void)n_in; (void)out_size;

    hipMemsetAsync(deg_cnt, 0, (size_t)NN * 4, stream);
    hipMemsetAsync(fill,    0, (size_t)NN * 4, stream);

    k_deg    <<<EE / 256, 256, 0, stream>>>(dstv, deg_cnt);
    k_norm   <<<NN / 256, 256, 0, stream>>>(deg_cnt, dinv, snorm);
    k_scan   <<<1, 1024, 0, stream>>>(deg_cnt, rowst);
    k_csrfill<<<EE / 256, 256, 0, stream>>>(srcv, dstv, rowst, fill, dinv, csr_src, csr_w);
    k_embed  <<<NN * 64 / 256, 256, 0, stream>>>(z, emb, xA);

    float* xc = xA;
    float* xn = xB;
    for (int layer = 0; layer < 3; layer++) {
        k_gemm_gcn<<<dim3(NN / 128, 2), 256, 0, stream>>>(xc, gcnw + (size_t)layer * 65536, xw);
        k_agg<<<NN / 4, 256, 0, stream>>>(xw, rowst, deg_cnt, csr_src, csr_w, snorm,
                                          gcnb + layer * 256, xn, h, layer * 256);
        float* t = xc; xc = xn; xn = t;
    }
    k_dot_last<<<NN / 4, 256, 0, stream>>>(xc, wlast, xwl);
    k_agg_last<<<NN / 256, 256, 0, stream>>>(xwl, rowst, deg_cnt, csr_src, csr_w, snorm, blast, h);

    k_sort_gather<<<GG, 128, 0, stream>>>(h, P);

    k_conv<<<dim3(GG, (C2LEN + JT - 1) / JT), 256, 0, stream>>>(P, w1, b1, w2, b2, fbuf);

    k_lin1  <<<dim3(4, L1_KS), 256, 0, stream>>>(fbuf, l1w, partial);
    k_reduce<<<GG, 128, 0, stream>>>(partial, l1b, l2w, l2b, out);
}

// Round 5
// 1454.255 us; speedup vs baseline: 15.4924x; 1.0155x over previous
//
#include <hip/hip_runtime.h>

// ---------------- problem constants ----------------
#define NN      32768       // nodes
#define EE      524288      // edges
#define GG      256         // graphs
#define NPG     128
#define HID     256
#define KTOP    30
#define TD      769         // HID*3+1
#define HSTR    772         // padded row stride for h (float4 aligned)
#define PLEN    23070       // KTOP*TD
#define C1LEN   23066
#define POOLLEN 11533
#define C2LEN   11529
#define FLAT    368928      // 32*C2LEN
#define L1_KRANGE 1024
#define L1_KS   361         // 360*1024=368640, last chunk 288 (both %16==0)

// ---------------- graph prep ----------------
__global__ __launch_bounds__(256) void k_deg(const int* __restrict__ dst, int* __restrict__ deg_cnt) {
    int e = blockIdx.x * 256 + threadIdx.x;
    atomicAdd(&deg_cnt[dst[e]], 1);
}

__global__ __launch_bounds__(256) void k_norm(const int* __restrict__ deg_cnt,
                                              float* __restrict__ dinv, float* __restrict__ snorm) {
    int n = blockIdx.x * 256 + threadIdx.x;
    float dg = 1.0f + (float)deg_cnt[n];
    dinv[n] = rsqrtf(dg);
    snorm[n] = 1.0f / dg;
}

// single-block exclusive scan of deg_cnt[NN] -> row_start[NN]
__global__ __launch_bounds__(1024) void k_scan(const int* __restrict__ deg_cnt, int* __restrict__ row_start) {
    __shared__ int sA[1024];
    int t = threadIdx.x;
    int base = t * 32;
    int s = 0;
    for (int i = 0; i < 32; i++) s += deg_cnt[base + i];
    sA[t] = s;
    __syncthreads();
    for (int off = 1; off < 1024; off <<= 1) {
        int v = (t >= off) ? sA[t - off] : 0;
        __syncthreads();
        sA[t] += v;
        __syncthreads();
    }
    int run = sA[t] - s;   // exclusive base for this thread's chunk
    for (int i = 0; i < 32; i++) { row_start[base + i] = run; run += deg_cnt[base + i]; }
}

__global__ __launch_bounds__(256) void k_csrfill(const int* __restrict__ src, const int* __restrict__ dst,
                                                 const int* __restrict__ row_start, int* __restrict__ fill,
                                                 const float* __restrict__ dinv,
                                                 int* __restrict__ csr_src, float* __restrict__ csr_w) {
    int e = blockIdx.x * 256 + threadIdx.x;
    int s = src[e], d = dst[e];
    int pos = row_start[d] + atomicAdd(&fill[d], 1);
    csr_src[pos] = s;
    csr_w[pos] = dinv[s] * dinv[d];
}

__global__ __launch_bounds__(256) void k_embed(const int* __restrict__ z, const float* __restrict__ emb,
                                               float* __restrict__ x) {
    int i = blockIdx.x * 256 + threadIdx.x;   // over NN*64
    int n = i >> 6, l = i & 63;
    ((float4*)x)[(size_t)n * 64 + l] = ((const float4*)emb)[(size_t)z[n] * 64 + l];
}

// ---------------- GCN GEMM: C[M,256] = A[M,256] @ B[256,256] ----------------
// BM=128 BN=128 BK=16, 256 threads, 8x8 per thread
__global__ __launch_bounds__(256) void k_gemm_gcn(const float* __restrict__ A, const float* __restrict__ B,
                                                  float* __restrict__ C) {
    __shared__ float As[16][132];
    __shared__ float Bs[16][132];
    int m0 = blockIdx.x * 128;
    int n0 = blockIdx.y * 128;
    int tid = threadIdx.x;
    int ty = tid >> 4, tx = tid & 15;
    float acc[8][8] = {};
    for (int k0 = 0; k0 < 256; k0 += 16) {
        {
            int m = tid >> 2, kq = (tid & 3) * 4;
            #pragma unroll
            for (int r = 0; r < 2; r++) {
                float4 v = *(const float4*)&A[(size_t)(m0 + m + 64 * r) * 256 + k0 + kq];
                As[kq + 0][m + 64 * r] = v.x;
                As[kq + 1][m + 64 * r] = v.y;
                As[kq + 2][m + 64 * r] = v.z;
                As[kq + 3][m + 64 * r] = v.w;
            }
            int n = (tid & 31) * 4, kk = tid >> 5;
            #pragma unroll
            for (int r = 0; r < 2; r++) {
                float4 v = *(const float4*)&B[(size_t)(k0 + kk + 8 * r) * 256 + n0 + n];
                *(float4*)&Bs[kk + 8 * r][n] = v;
            }
        }
        __syncthreads();
        #pragma unroll
        for (int k = 0; k < 16; k++) {
            float a[8], b[8];
            *(float4*)&a[0] = *(float4*)&As[k][ty * 8];
            *(float4*)&a[4] = *(float4*)&As[k][ty * 8 + 4];
            *(float4*)&b[0] = *(float4*)&Bs[k][tx * 8];
            *(float4*)&b[4] = *(float4*)&Bs[k][tx * 8 + 4];
            #pragma unroll
            for (int i = 0; i < 8; i++)
                #pragma unroll
                for (int j = 0; j < 8; j++) acc[i][j] += a[i] * b[j];
        }
        __syncthreads();
    }
    #pragma unroll
    for (int i = 0; i < 8; i++) {
        int m = m0 + ty * 8 + i;
        float4 v0 = make_float4(acc[i][0], acc[i][1], acc[i][2], acc[i][3]);
        float4 v1 = make_float4(acc[i][4], acc[i][5], acc[i][6], acc[i][7]);
        *(float4*)&C[(size_t)m * 256 + n0 + tx * 8] = v0;
        *(float4*)&C[(size_t)m * 256 + n0 + tx * 8 + 4] = v1;
    }
}

// ---------------- aggregation + tanh, one wave per node ----------------
// If wl != nullptr, also computes xwl[d] = dot(tanh_row, wl) (fused k_dot_last).
__global__ __launch_bounds__(256) void k_agg(const float* __restrict__ xw, const int* __restrict__ row_start,
                                             const int* __restrict__ deg_cnt, const int* __restrict__ csr_src,
                                             const float* __restrict__ csr_w, const float* __restrict__ snorm,
                                             const float* __restrict__ bias, float* __restrict__ xn,
                                             float* __restrict__ h, int hoff,
                                             const float* __restrict__ wl, float* __restrict__ xwl) {
    int d = blockIdx.x * 4 + (threadIdx.x >> 6);
    int l = threadIdx.x & 63;
    float4 v = ((const float4*)xw)[(size_t)d * 64 + l];
    float sn = snorm[d];
    float4 acc = make_float4(sn * v.x, sn * v.y, sn * v.z, sn * v.w);
    int st = row_start[d], cnt = deg_cnt[d];
    for (int j = 0; j < cnt; j++) {
        int s = csr_src[st + j];
        float w = csr_w[st + j];
        float4 u = ((const float4*)xw)[(size_t)s * 64 + l];
        acc.x += w * u.x; acc.y += w * u.y; acc.z += w * u.z; acc.w += w * u.w;
    }
    float4 b = ((const float4*)bias)[l];
    acc.x = tanhf(acc.x + b.x);
    acc.y = tanhf(acc.y + b.y);
    acc.z = tanhf(acc.z + b.z);
    acc.w = tanhf(acc.w + b.w);
    ((float4*)xn)[(size_t)d * 64 + l] = acc;
    *(float4*)&h[(size_t)d * HSTR + hoff + l * 4] = acc;
    if (wl != nullptr) {
        float4 w4 = ((const float4*)wl)[l];
        float s = acc.x * w4.x + acc.y * w4.y + acc.z * w4.z + acc.w * w4.w;
        #pragma unroll
        for (int off = 32; off; off >>= 1) s += __shfl_down(s, off, 64);
        if (l == 0) xwl[d] = s;
    }
}

__global__ __launch_bounds__(256) void k_agg_last(const float* __restrict__ xwl, const int* __restrict__ row_start,
                                                  const int* __restrict__ deg_cnt, const int* __restrict__ csr_src,
                                                  const float* __restrict__ csr_w, const float* __restrict__ snorm,
                                                  const float* __restrict__ blast, float* __restrict__ h) {
    int d = blockIdx.x * 256 + threadIdx.x;
    float acc = snorm[d] * xwl[d];
    int st = row_start[d], cnt = deg_cnt[d];
    for (int j = 0; j < cnt; j++) acc += csr_w[st + j] * xwl[csr_src[st + j]];
    h[(size_t)d * HSTR + 768] = tanhf(acc + blast[0]);
}

// ---------- per-graph stable top-K sort (bitonic over 128) + gather into P ----------
__global__ __launch_bounds__(128) void k_sort_gather(const float* __restrict__ h, float* __restrict__ P) {
    __shared__ float kk[128];
    __shared__ int ii[128];
    int g = blockIdx.x, t = threadIdx.x;
    kk[t] = h[(size_t)(g * 128 + t) * HSTR + 768];
    ii[t] = t;
    __syncthreads();
    for (int size = 2; size <= 128; size <<= 1) {
        for (int stride = size >> 1; stride > 0; stride >>= 1) {
            int p = t ^ stride;
            if (p > t) {
                float ka = kk[t], kbv = kk[p];
                int ia = ii[t], ib = ii[p];
                // aFirst: a precedes b in final order (desc key, asc idx on ties == stable argsort(-key))
                bool aFirst = (ka > kbv) || (ka == kbv && ia < ib);
                bool asc = (t & size) == 0;
                if (asc != aFirst) { kk[t] = kbv; kk[p] = ka; ii[t] = ib; ii[p] = ia; }
            }
            __syncthreads();
        }
    }
    // gather top-K rows of h into P
    float* Pg = P + (size_t)g * PLEN;
    for (int r = 0; r < KTOP; r++) {
        const float* srcp = h + (size_t)(g * 128 + ii[r]) * HSTR;
        for (int c = t; c < TD; c += 128) Pg[(size_t)r * TD + c] = srcp[c];
    }
}

// ---------------- fused conv1 + relu + maxpool2 + conv2 + relu ----------------
// Round-3 postmortem: 29% of k_conv cycles were LDS bank-conflict stall from
// stride-2 sl[2t+q] reads in the pool phase. Fix: split sl into even/odd
// arrays -> all pool-phase reads are stride-1 (conflict-free), and the
// (2t, 2t+1) pair shares 4 of 6 loads. Register budget unchanged (VGPR 36,
// 16 accs/thread, c1 loop unroll 4 -- full unroll spilled in round 2).
#define JT 128
__global__ __launch_bounds__(256) void k_conv(const float* __restrict__ P,
                                              const float* __restrict__ w1, const float* __restrict__ b1,
                                              const float* __restrict__ w2, const float* __restrict__ b2,
                                              float* __restrict__ f) {
    __shared__ float sle[136];           // sl[2i]   for i in [0,134)
    __shared__ float slo[136];           // sl[2i+1] for i in [0,134)
    __shared__ float pool[16][136];      // pooled conv1 outputs, local t in [0,132)
    __shared__ float w2t[80][32];        // w2 transposed: [c1*5+k][c2]
    __shared__ float w1s[16][5];
    __shared__ float b1s[16];
    __shared__ float b2s[32];
    int g = blockIdx.x;
    int j0 = blockIdx.y * JT;
    int tid = threadIdx.x;
    const float* Pg = P + (size_t)g * PLEN;
    for (int i = tid; i < 268; i += 256) {
        float v = Pg[min(2 * j0 + i, PLEN - 1)];
        if (i & 1) slo[i >> 1] = v; else sle[i >> 1] = v;
    }
    for (int i = tid; i < 80; i += 256) w1s[i / 5][i % 5] = w1[i];
    if (tid < 16) b1s[tid] = b1[tid];
    if (tid < 32) b2s[tid] = b2[tid];
    for (int i = tid; i < 2560; i += 256) {
        int c2 = i / 80, rem = i % 80;     // rem = c1*5+k
        w2t[rem][c2] = w2[i];
    }
    __syncthreads();
    // pool build: conv1[2t], conv1[2t+1] from stride-1 e/o reads, then max+relu
    for (int i = tid; i < 16 * 132; i += 256) {
        int c1 = i / 132, t = i % 132;
        float e0 = sle[t], o0 = slo[t], e1 = sle[t + 1], o1 = slo[t + 1], e2 = sle[t + 2], o2 = slo[t + 2];
        float w0 = w1s[c1][0], w1v = w1s[c1][1], w2v = w1s[c1][2], w3 = w1s[c1][3], w4 = w1s[c1][4];
        float a = b1s[c1] + w0 * e0 + w1v * o0 + w2v * e1 + w3 * o1 + w4 * e2;
        float b = b1s[c1] + w0 * o0 + w1v * e1 + w2v * o1 + w3 * e2 + w4 * o2;
        pool[c1][t] = fmaxf(fmaxf(a, b), 0.0f);
    }
    __syncthreads();
    // conv2: wave wv -> c2 block [wv*8, wv*8+8), lane jl -> j in {j0+jl, j0+jl+64}
    int wv = tid >> 6;
    int jl = tid & 63;
    int c2o = wv * 8;
    float acc[8][2];
    #pragma unroll
    for (int cc = 0; cc < 8; cc++) {
        float bb = b2s[c2o + cc];
        acc[cc][0] = bb; acc[cc][1] = bb;
    }
    #pragma unroll 4
    for (int c1 = 0; c1 < 16; c1++) {
        #pragma unroll
        for (int k = 0; k < 5; k++) {
            float4 w0 = *(float4*)&w2t[c1 * 5 + k][c2o];
            float4 w1v = *(float4*)&w2t[c1 * 5 + k][c2o + 4];
            float p0 = pool[c1][jl + k];
            float p1 = pool[c1][jl + 64 + k];
            acc[0][0] += w0.x * p0; acc[0][1] += w0.x * p1;
            acc[1][0] += w0.y * p0; acc[1][1] += w0.y * p1;
            acc[2][0] += w0.z * p0; acc[2][1] += w0.z * p1;
            acc[3][0] += w0.w * p0; acc[3][1] += w0.w * p1;
            acc[4][0] += w1v.x * p0; acc[4][1] += w1v.x * p1;
            acc[5][0] += w1v.y * p0; acc[5][1] += w1v.y * p1;
            acc[6][0] += w1v.z * p0; acc[6][1] += w1v.z * p1;
            acc[7][0] += w1v.w * p0; acc[7][1] += w1v.w * p1;
        }
    }
    size_t fg = (size_t)g * FLAT;
    #pragma unroll
    for (int cc = 0; cc < 8; cc++) {
        #pragma unroll
        for (int jj = 0; jj < 2; jj++) {
            int j = j0 + jl + 64 * jj;
            if (j < C2LEN) f[fg + (size_t)(c2o + cc) * C2LEN + j] = fmaxf(acc[cc][jj], 0.0f);
        }
    }
}

// ---------------- lin1 split-K GEMM: C[256,128] = f[256,FLAT] @ W[128,FLAT]^T ----------------
// BM=128 BN=128 BK=16, 256 threads, 8x8 per thread (same structure as k_gemm_gcn).
// L1_KRANGE=1024 -> grid (2, 361) = 722 blocks = ~2.8 waves/SIMD (2048 was 1.4 -- too thin).
__global__ __launch_bounds__(256) void k_lin1(const float* __restrict__ f, const float* __restrict__ W,
                                              float* __restrict__ partial) {
    __shared__ float As[16][132];
    __shared__ float Bs[16][132];
    int m0 = blockIdx.x * 128;
    int ks = blockIdx.y;
    int kbase = ks * L1_KRANGE;
    int kend = min(kbase + L1_KRANGE, FLAT);
    int tid = threadIdx.x;
    int ty = tid >> 4, tx = tid & 15;
    float acc[8][8] = {};
    for (int k0 = kbase; k0 < kend; k0 += 16) {
        {
            // A tile: 128 rows (graphs) x 16 k
            int m = tid >> 2, kq = (tid & 3) * 4;
            #pragma unroll
            for (int r = 0; r < 2; r++) {
                float4 v = *(const float4*)&f[(size_t)(m0 + m + 64 * r) * FLAT + k0 + kq];
                As[kq + 0][m + 64 * r] = v.x;
                As[kq + 1][m + 64 * r] = v.y;
                As[kq + 2][m + 64 * r] = v.z;
                As[kq + 3][m + 64 * r] = v.w;
            }
            // B tile: W is [128 o][FLAT k] (row-major) -> scatter to Bs[k][o]
            int n = tid >> 1, kq2 = (tid & 1) * 8;
            #pragma unroll
            for (int r = 0; r < 2; r++) {
                int k = kq2 + r * 4;
                float4 v = *(const float4*)&W[(size_t)n * FLAT + k0 + k];
                Bs[k + 0][n] = v.x; Bs[k + 1][n] = v.y; Bs[k + 2][n] = v.z; Bs[k + 3][n] = v.w;
            }
        }
        __syncthreads();
        #pragma unroll
        for (int k = 0; k < 16; k++) {
            float a[8], b[8];
            *(float4*)&a[0] = *(float4*)&As[k][ty * 8];
            *(float4*)&a[4] = *(float4*)&As[k][ty * 8 + 4];
            *(float4*)&b[0] = *(float4*)&Bs[k][tx * 8];
            *(float4*)&b[4] = *(float4*)&Bs[k][tx * 8 + 4];
            #pragma unroll
            for (int i = 0; i < 8; i++)
                #pragma unroll
                for (int j = 0; j < 8; j++) acc[i][j] += a[i] * b[j];
        }
        __syncthreads();
    }
    #pragma unroll
    for (int i = 0; i < 8; i++) {
        int m = m0 + ty * 8 + i;
        float4 v0 = make_float4(acc[i][0], acc[i][1], acc[i][2], acc[i][3]);
        float4 v1 = make_float4(acc[i][4], acc[i][5], acc[i][6], acc[i][7]);
        *(float4*)&partial[((size_t)ks * 256 + m) * 128 + tx * 8] = v0;
        *(float4*)&partial[((size_t)ks * 256 + m) * 128 + tx * 8 + 4] = v1;
    }
}

// ---------------- reduce partials + relu + lin2 ----------------
__global__ __launch_bounds__(128) void k_reduce(const float* __restrict__ partial, const float* __restrict__ lb1,
                                                const float* __restrict__ lw2, const float* __restrict__ lb2,
                                                float* __restrict__ out) {
    int g = blockIdx.x, o = threadIdx.x;
    float s = 0.0f;
    for (int ks = 0; ks < L1_KS; ks++) s += partial[((size_t)ks * 256 + g) * 128 + o];
    float v = fmaxf(s + lb1[o], 0.0f) * lw2[o];
    #pragma unroll
    for (int off = 32; off; off >>= 1) v += __shfl_down(v, off, 64);
    __shared__ float red[2];
    if ((threadIdx.x & 63) == 0) red[threadIdx.x >> 6] = v;
    __syncthreads();
    if (threadIdx.x == 0) out[g] = red[0] + red[1] + lb2[0];
}

// ---------------- host launch ----------------
extern "C" void kernel_launch(void* const* d_in, const int* in_sizes, int n_in,
                              void* d_out, int out_size, void* d_ws, size_t ws_size,
                              hipStream_t stream) {
    const int*   z     = (const int*)d_in[0];
    const int*   ei    = (const int*)d_in[1];
    const int*   srcv  = ei;
    const int*   dstv  = ei + EE;
    const float* emb   = (const float*)d_in[3];
    const float* gcnw  = (const float*)d_in[4];
    const float* gcnb  = (const float*)d_in[5];
    const float* wlast = (const float*)d_in[6];
    const float* blast = (const float*)d_in[7];
    const float* w1    = (const float*)d_in[8];
    const float* b1    = (const float*)d_in[9];
    const float* w2    = (const float*)d_in[10];
    const float* b2    = (const float*)d_in[11];
    const float* l1w   = (const float*)d_in[12];
    const float* l1b   = (const float*)d_in[13];
    const float* l2w   = (const float*)d_in[14];
    const float* l2b   = (const float*)d_in[15];
    float* out = (float*)d_out;

    // ---- workspace layout with aliasing (~449 MB total) ----
    // fbuf occupies [0, FB). All stage-1 buffers live INSIDE [0, FB): they are
    // dead before k_conv writes fbuf (last stage-1 reader is k_sort_gather).
    // P and partial live after FB (P is read by k_conv while fbuf is written).
    char* base = (char*)d_ws;
    const size_t FB = ((size_t)GG * FLAT * 4 + 511) & ~(size_t)511;   // 377.8 MB
    float* fbuf = (float*)base;
    char* p = base;
    auto alloc = [&](size_t bytes) { void* r = (void*)p; p += (bytes + 511) & ~(size_t)511; return r; };
    int*   deg_cnt = (int*)  alloc((size_t)NN * 4);
    int*   fill    = (int*)  alloc((size_t)NN * 4);
    int*   rowst   = (int*)  alloc((size_t)NN * 4);
    int*   csr_src = (int*)  alloc((size_t)EE * 4);
    float* csr_w   = (float*)alloc((size_t)EE * 4);
    float* dinv    = (float*)alloc((size_t)NN * 4);
    float* snorm   = (float*)alloc((size_t)NN * 4);
    float* xA      = (float*)alloc((size_t)NN * 256 * 4);
    float* xB      = (float*)alloc((size_t)NN * 256 * 4);
    float* xw      = (float*)alloc((size_t)NN * 256 * 4);
    float* h       = (float*)alloc((size_t)NN * HSTR * 4);
    float* xwl     = (float*)alloc((size_t)NN * 4);
    // stage-1 total ~207 MB < FB (378 MB): fits inside the fbuf overlay region.
    float* P       = (float*)(base + FB);
    float* partial = (float*)(base + FB + (((size_t)GG * PLEN * 4 + 511) & ~(size_t)511));
    (void)ws_size; (void)in_sizes; (void)n_in; (void)out_size;

    hipMemsetAsync(deg_cnt, 0, (size_t)NN * 4, stream);
    hipMemsetAsync(fill,    0, (size_t)NN * 4, stream);

    k_deg    <<<EE / 256, 256, 0, stream>>>(dstv, deg_cnt);
    k_norm   <<<NN / 256, 256, 0, stream>>>(deg_cnt, dinv, snorm);
    k_scan   <<<1, 1024, 0, stream>>>(deg_cnt, rowst);
    k_csrfill<<<EE / 256, 256, 0, stream>>>(srcv, dstv, rowst, fill, dinv, csr_src, csr_w);
    k_embed  <<<NN * 64 / 256, 256, 0, stream>>>(z, emb, xA);

    float* xc = xA;
    float* xn = xB;
    for (int layer = 0; layer < 3; layer++) {
        k_gemm_gcn<<<dim3(NN / 128, 2), 256, 0, stream>>>(xc, gcnw + (size_t)layer * 65536, xw);
        // fuse xwl = x3 . wlast into the last agg (saves k_dot_last + 32 MB re-read)
        const float* wl = (layer == 2) ? wlast : nullptr;
        k_agg<<<NN / 4, 256, 0, stream>>>(xw, rowst, deg_cnt, csr_src, csr_w, snorm,
                                          gcnb + layer * 256, xn, h, layer * 256, wl, xwl);
        float* t = xc; xc = xn; xn = t;
    }
    k_agg_last<<<NN / 256, 256, 0, stream>>>(xwl, rowst, deg_cnt, csr_src, csr_w, snorm, blast, h);

    k_sort_gather<<<GG, 128, 0, stream>>>(h, P);

    k_conv<<<dim3(GG, (C2LEN + JT - 1) / JT), 256, 0, stream>>>(P, w1, b1, w2, b2, fbuf);

    k_lin1  <<<dim3(2, L1_KS), 256, 0, stream>>>(fbuf, l1w, partial);
    k_reduce<<<GG, 128, 0, stream>>>(partial, l1b, l2w, l2b, out);
}